// Round 1
// baseline (653.988 us; speedup 1.0000x reference)
//
#include <hip/hip_runtime.h>
#include <hip/hip_bf16.h>

// Problem constants (from reference): B=4, N=4096 -> T=16384 tokens,
// D=1024, H=4*D=4096, OUT=1024, 4 nested experts.
#define T_TOK 16384
#define DMODEL 1024
#define HDIM 4096
#define OUTD 1024

typedef __attribute__((ext_vector_type(8))) short short8_t;  // 8 x bf16 (4 VGPRs)
typedef __attribute__((ext_vector_type(4))) float f32x4;     // MFMA accumulator

// ---- ws layout ----
// [0]      int counts[4]
// [64]     unsigned long long hbase[4]   (element offsets into hbuf)
// [128]    int list[4 * T_TOK]           (token ids grouped by expert)
// [512KB]  short hbuf[...]               (compact bf16 hidden activations, ~63MB)
#define WS_COUNTS_OFF 0
#define WS_HBASE_OFF 64
#define WS_LIST_OFF 128
#define WS_HBUF_OFF (512 * 1024)

__device__ __forceinline__ short f2bf(float f) {
    union { float f; unsigned u; } x; x.f = f;
    unsigned r = x.u + 0x7FFFu + ((x.u >> 16) & 1u);  // RNE
    return (short)(r >> 16);
}

__device__ __forceinline__ float gelu_exact(float v) {
    return 0.5f * v * (1.0f + erff(v * 0.7071067811865476f));
}

__global__ void k_init(int* counts) {
    if (threadIdx.x < 4) counts[threadIdx.x] = 0;
}

__global__ void k_build(const int* __restrict__ mask, int* counts, int* list) {
    int t = blockIdx.x * blockDim.x + threadIdx.x;
    if (t < T_TOK) {
        int e = mask[t] & 3;
        int pos = atomicAdd(&counts[e], 1);
        list[e * T_TOK + pos] = t;
    }
}

__global__ void k_bases(const int* counts, unsigned long long* hbase) {
    if (threadIdx.x == 0) {
        unsigned long long acc = 0;
        for (int e = 0; e < 4; ++e) {
            hbase[e] = acc;
            int d_hid = (DMODEL >> (3 - e)) * 4;
            acc += (unsigned long long)counts[e] * (unsigned long long)d_hid;
        }
    }
}

// ---------------------------------------------------------------------------
// Pass 1: h = gelu(x[:, :d_in] @ W1[:d_hid, :d_in]^T + b1[:d_hid])  (bf16 out)
// Tile: 128 tokens x 128 hidden, BK=64. 4 waves, each 64x64 via 4x4 grid of
// mfma_f32_16x16x32_bf16. LDS chunks XOR-swizzled for read-side bank spread.
// ---------------------------------------------------------------------------
__global__ __launch_bounds__(256) void k_pass1(
    const float* __restrict__ x, const float* __restrict__ w1,
    const float* __restrict__ b1,
    const int* __restrict__ counts, const unsigned long long* __restrict__ hbase,
    const int* __restrict__ list, short* __restrict__ hbuf)
{
    const int e = blockIdx.z;
    const int shift = 3 - e;
    const int d_in = DMODEL >> shift;
    const int d_hid = d_in * 4;
    const int n0 = blockIdx.y * 128;
    if (n0 >= d_hid) return;
    const int cnt = counts[e];
    const int m0 = blockIdx.x * 128;
    if (m0 >= cnt) return;
    const int* lst = list + e * T_TOK;
    const unsigned long long hb = hbase[e];

    __shared__ short Abuf[128 * 64];
    __shared__ short Bbuf[128 * 64];

    const int tid = threadIdx.x;
    const int lane = tid & 63;
    const int wid = tid >> 6;
    const int wm = (wid >> 1) * 64;
    const int wn = (wid & 1) * 64;

    f32x4 acc[4][4];
#pragma unroll
    for (int i = 0; i < 4; ++i)
#pragma unroll
        for (int j = 0; j < 4; ++j)
            acc[i][j] = (f32x4){0.f, 0.f, 0.f, 0.f};

    for (int k0 = 0; k0 < d_in; k0 += 64) {
        // stage A (gathered token rows, fp32 -> bf16) and B (w1 rows)
#pragma unroll
        for (int it = 0; it < 4; ++it) {
            int c = tid + it * 256;          // chunk id 0..1023 (16B chunks)
            int row = c >> 3, ch = c & 7;
            int dst = ((row << 3) | (ch ^ (row & 7))) << 3;  // swizzled, in shorts
            {
                int rr = m0 + row; if (rr >= cnt) rr = cnt - 1;
                int tok = lst[rr];
                const float4* src = (const float4*)(x + (size_t)tok * DMODEL + k0 + ch * 8);
                float4 f0 = src[0], f1 = src[1];
                short8_t v;
                v[0] = f2bf(f0.x); v[1] = f2bf(f0.y); v[2] = f2bf(f0.z); v[3] = f2bf(f0.w);
                v[4] = f2bf(f1.x); v[5] = f2bf(f1.y); v[6] = f2bf(f1.z); v[7] = f2bf(f1.w);
                *(short8_t*)&Abuf[dst] = v;
            }
            {
                const float4* src = (const float4*)(w1 + (size_t)(n0 + row) * DMODEL + k0 + ch * 8);
                float4 f0 = src[0], f1 = src[1];
                short8_t v;
                v[0] = f2bf(f0.x); v[1] = f2bf(f0.y); v[2] = f2bf(f0.z); v[3] = f2bf(f0.w);
                v[4] = f2bf(f1.x); v[5] = f2bf(f1.y); v[6] = f2bf(f1.z); v[7] = f2bf(f1.w);
                *(short8_t*)&Bbuf[dst] = v;
            }
        }
        __syncthreads();
#pragma unroll
        for (int kk = 0; kk < 2; ++kk) {
            short8_t af[4], bfr[4];
            const int q = (lane >> 4) + kk * 4;
#pragma unroll
            for (int mt = 0; mt < 4; ++mt) {
                int row = wm + mt * 16 + (lane & 15);
                af[mt] = *(const short8_t*)&Abuf[((row << 3) | (q ^ (row & 7))) << 3];
            }
#pragma unroll
            for (int nt = 0; nt < 4; ++nt) {
                int row = wn + nt * 16 + (lane & 15);
                bfr[nt] = *(const short8_t*)&Bbuf[((row << 3) | (q ^ (row & 7))) << 3];
            }
#pragma unroll
            for (int mt = 0; mt < 4; ++mt)
#pragma unroll
                for (int nt = 0; nt < 4; ++nt)
                    acc[mt][nt] = __builtin_amdgcn_mfma_f32_16x16x32_bf16(
                        af[mt], bfr[nt], acc[mt][nt], 0, 0, 0);
        }
        __syncthreads();
    }

    // epilogue: +b1, exact gelu, bf16 store to compact hbuf
    const int col_l = lane & 15;
    const int qr = lane >> 4;
#pragma unroll
    for (int nt = 0; nt < 4; ++nt) {
        int col = n0 + wn + nt * 16 + col_l;
        float bias = b1[col];
#pragma unroll
        for (int mt = 0; mt < 4; ++mt) {
#pragma unroll
            for (int r = 0; r < 4; ++r) {
                int row = wm + mt * 16 + qr * 4 + r;
                if (m0 + row < cnt) {
                    float v = acc[mt][nt][r] + bias;
                    hbuf[hb + (unsigned long long)(m0 + row) * d_hid + col] =
                        f2bf(gelu_exact(v));
                }
            }
        }
    }
}

// ---------------------------------------------------------------------------
// Pass 2: y[tok, :d_out] = h @ W2[:d_out, :d_hid]^T + b2[:d_out]
// Same tile structure; A comes from bf16 hbuf (no conversion).
// ---------------------------------------------------------------------------
__global__ __launch_bounds__(256) void k_pass2(
    const short* __restrict__ hbuf, const float* __restrict__ w2,
    const float* __restrict__ b2,
    const int* __restrict__ counts, const unsigned long long* __restrict__ hbase,
    const int* __restrict__ list, float* __restrict__ y)
{
    const int e = blockIdx.z;
    const int shift = 3 - e;
    const int d_in = DMODEL >> shift;
    const int d_hid = d_in * 4;
    const int d_out = OUTD >> shift;
    const int n0 = blockIdx.y * 128;
    if (n0 >= d_out) return;
    const int cnt = counts[e];
    const int m0 = blockIdx.x * 128;
    if (m0 >= cnt) return;
    const int* lst = list + e * T_TOK;
    const unsigned long long hb = hbase[e];

    __shared__ short Abuf[128 * 64];
    __shared__ short Bbuf[128 * 64];

    const int tid = threadIdx.x;
    const int lane = tid & 63;
    const int wid = tid >> 6;
    const int wm = (wid >> 1) * 64;
    const int wn = (wid & 1) * 64;

    f32x4 acc[4][4];
#pragma unroll
    for (int i = 0; i < 4; ++i)
#pragma unroll
        for (int j = 0; j < 4; ++j)
            acc[i][j] = (f32x4){0.f, 0.f, 0.f, 0.f};

    for (int k0 = 0; k0 < d_hid; k0 += 64) {
#pragma unroll
        for (int it = 0; it < 4; ++it) {
            int c = tid + it * 256;
            int row = c >> 3, ch = c & 7;
            int dst = ((row << 3) | (ch ^ (row & 7))) << 3;
            {
                int rr = m0 + row; if (rr >= cnt) rr = cnt - 1;
                short8_t v = *(const short8_t*)&hbuf[hb + (unsigned long long)rr * d_hid + k0 + ch * 8];
                *(short8_t*)&Abuf[dst] = v;
            }
            {
                const float4* src = (const float4*)(w2 + (size_t)(n0 + row) * HDIM + k0 + ch * 8);
                float4 f0 = src[0], f1 = src[1];
                short8_t v;
                v[0] = f2bf(f0.x); v[1] = f2bf(f0.y); v[2] = f2bf(f0.z); v[3] = f2bf(f0.w);
                v[4] = f2bf(f1.x); v[5] = f2bf(f1.y); v[6] = f2bf(f1.z); v[7] = f2bf(f1.w);
                *(short8_t*)&Bbuf[dst] = v;
            }
        }
        __syncthreads();
#pragma unroll
        for (int kk = 0; kk < 2; ++kk) {
            short8_t af[4], bfr[4];
            const int q = (lane >> 4) + kk * 4;
#pragma unroll
            for (int mt = 0; mt < 4; ++mt) {
                int row = wm + mt * 16 + (lane & 15);
                af[mt] = *(const short8_t*)&Abuf[((row << 3) | (q ^ (row & 7))) << 3];
            }
#pragma unroll
            for (int nt = 0; nt < 4; ++nt) {
                int row = wn + nt * 16 + (lane & 15);
                bfr[nt] = *(const short8_t*)&Bbuf[((row << 3) | (q ^ (row & 7))) << 3];
            }
#pragma unroll
            for (int mt = 0; mt < 4; ++mt)
#pragma unroll
                for (int nt = 0; nt < 4; ++nt)
                    acc[mt][nt] = __builtin_amdgcn_mfma_f32_16x16x32_bf16(
                        af[mt], bfr[nt], acc[mt][nt], 0, 0, 0);
        }
        __syncthreads();
    }

    // epilogue: +b2, scatter fp32 to y rows (cols >= d_out pre-zeroed by memset)
    const int col_l = lane & 15;
    const int qr = lane >> 4;
#pragma unroll
    for (int nt = 0; nt < 4; ++nt) {
        int col = n0 + wn + nt * 16 + col_l;
        float bias = b2[col];
#pragma unroll
        for (int mt = 0; mt < 4; ++mt) {
#pragma unroll
            for (int r = 0; r < 4; ++r) {
                int row = wm + mt * 16 + qr * 4 + r;
                if (m0 + row < cnt) {
                    int tok = lst[m0 + row];
                    y[(size_t)tok * OUTD + col] = acc[mt][nt][r] + bias;
                }
            }
        }
    }
}

extern "C" void kernel_launch(void* const* d_in, const int* in_sizes, int n_in,
                              void* d_out, int out_size, void* d_ws, size_t ws_size,
                              hipStream_t stream) {
    const float* x  = (const float*)d_in[0];
    const int* mask = (const int*)d_in[1];
    const float* w1 = (const float*)d_in[2];
    const float* b1 = (const float*)d_in[3];
    const float* w2 = (const float*)d_in[4];
    const float* b2 = (const float*)d_in[5];
    float* y = (float*)d_out;

    char* ws = (char*)d_ws;
    int* counts = (int*)(ws + WS_COUNTS_OFF);
    unsigned long long* hbase = (unsigned long long*)(ws + WS_HBASE_OFF);
    int* list = (int*)(ws + WS_LIST_OFF);
    short* hbuf = (short*)(ws + WS_HBUF_OFF);

    // zero-fill output (covers cols >= d_out(e) per token)
    hipMemsetAsync(d_out, 0, (size_t)out_size * sizeof(float), stream);

    k_init<<<1, 64, 0, stream>>>(counts);
    k_build<<<T_TOK / 256, 256, 0, stream>>>(mask, counts, list);
    k_bases<<<1, 1, 0, stream>>>(counts, hbase);

    // pass1: grid covers worst case (all tokens on one expert): 128 m-tiles,
    // 32 hidden n-tiles, 4 experts; inactive blocks early-exit.
    k_pass1<<<dim3(128, 32, 4), 256, 0, stream>>>(x, w1, b1, counts, hbase, list, hbuf);
    // pass2: 8 out n-tiles max
    k_pass2<<<dim3(128, 8, 4), 256, 0, stream>>>(hbuf, w2, b2, counts, hbase, list, y);
}

// Round 2
// 547.507 us; speedup vs baseline: 1.1945x; 1.1945x over previous
//
#include <hip/hip_runtime.h>
#include <hip/hip_bf16.h>

// B=4, N=4096 -> T=16384 tokens, D=1024, H=4096, OUT=1024, 4 nested experts.
#define T_TOK 16384
#define DMODEL 1024
#define HDIM 4096
#define OUTD 1024

typedef __attribute__((ext_vector_type(8))) short short8_t;  // 8 x bf16
typedef __attribute__((ext_vector_type(4))) float f32x4;     // MFMA acc

// ---- ws layout (MB-aligned regions) ----
// [0]       int counts[4]
// [64]      unsigned long long hbase[4]
// [128]     int list[4 * T_TOK]
// [1 MB]    short xbf [16384*1024]   (32 MB)
// [34 MB]   short w1bf[4096*1024]    (8 MB)
// [43 MB]   short w2bf[1024*4096]    (8 MB)
// [52 MB]   short hbuf[...]          (~63 MB for near-uniform routing)
#define WS_COUNTS_OFF 0
#define WS_HBASE_OFF 64
#define WS_LIST_OFF 128
#define WS_XBF_OFF  ((size_t)1 << 20)
#define WS_W1BF_OFF ((size_t)34 << 20)
#define WS_W2BF_OFF ((size_t)43 << 20)
#define WS_HBUF_OFF ((size_t)52 << 20)

#define XN (T_TOK * DMODEL)      // 16777216
#define W1N (HDIM * DMODEL)      // 4194304
#define W2N (OUTD * HDIM)        // 4194304

__device__ __forceinline__ short f2bf(float f) {
    union { float f; unsigned u; } x; x.f = f;
    unsigned r = x.u + 0x7FFFu + ((x.u >> 16) & 1u);  // RNE
    return (short)(r >> 16);
}

__device__ __forceinline__ float gelu_exact(float v) {
    return 0.5f * v * (1.0f + erff(v * 0.7071067811865476f));
}

__device__ __forceinline__ void conv8(const float* __restrict__ s, short* __restrict__ d) {
    const float4* s4 = (const float4*)s;
    float4 f0 = s4[0], f1 = s4[1];
    short8_t v;
    v[0] = f2bf(f0.x); v[1] = f2bf(f0.y); v[2] = f2bf(f0.z); v[3] = f2bf(f0.w);
    v[4] = f2bf(f1.x); v[5] = f2bf(f1.y); v[6] = f2bf(f1.z); v[7] = f2bf(f1.w);
    *(short8_t*)d = v;
}

// async global->LDS, 16B per lane; LDS dest = wave-uniform base + lane*16
__device__ __forceinline__ void gl_lds16(const short* g, short* lds) {
    __builtin_amdgcn_global_load_lds(
        (const __attribute__((address_space(1))) void*)g,
        (__attribute__((address_space(3))) void*)lds, 16, 0, 0);
}

__global__ void k_convert(const float* __restrict__ x, const float* __restrict__ w1,
                          const float* __restrict__ w2, short* __restrict__ xbf,
                          short* __restrict__ w1bf, short* __restrict__ w2bf) {
    size_t i8 = (size_t)blockIdx.x * blockDim.x + threadIdx.x;
    size_t elem = i8 * 8;
    if (elem < (size_t)XN) {
        conv8(x + elem, xbf + elem);
    } else if (elem < (size_t)XN + W1N) {
        size_t o = elem - XN; conv8(w1 + o, w1bf + o);
    } else {
        size_t o = elem - XN - W1N; conv8(w2 + o, w2bf + o);
    }
}

__global__ void k_init(int* counts) {
    if (threadIdx.x < 4) counts[threadIdx.x] = 0;
}

__global__ void k_build(const int* __restrict__ mask, int* counts, int* list) {
    int t = blockIdx.x * blockDim.x + threadIdx.x;
    if (t < T_TOK) {
        int e = mask[t] & 3;
        int pos = atomicAdd(&counts[e], 1);
        list[e * T_TOK + pos] = t;
    }
}

__global__ void k_bases(const int* counts, unsigned long long* hbase) {
    if (threadIdx.x == 0) {
        unsigned long long acc = 0;
        for (int e = 0; e < 4; ++e) {
            hbase[e] = acc;
            int d_hid = (DMODEL >> (3 - e)) * 4;
            acc += (unsigned long long)counts[e] * (unsigned long long)d_hid;
        }
    }
}

// ---------------------------------------------------------------------------
// Pass 1: h = gelu(x[:, :d_in] @ W1[:d_hid, :d_in]^T + b1)  (bf16, DMA staged)
// blockIdx.y in [0,60) -> (e, ntile): e0:4, e1:8, e2:16, e3:32 tiles.
// ---------------------------------------------------------------------------
__global__ __launch_bounds__(256) void k_pass1(
    const short* __restrict__ xbf, const short* __restrict__ w1bf,
    const float* __restrict__ b1,
    const int* __restrict__ counts, const unsigned long long* __restrict__ hbase,
    const int* __restrict__ list, short* __restrict__ hbuf)
{
    int by = blockIdx.y;
    int e, nt;
    if (by < 4)       { e = 0; nt = by; }
    else if (by < 12) { e = 1; nt = by - 4; }
    else if (by < 28) { e = 2; nt = by - 12; }
    else              { e = 3; nt = by - 28; }
    const int shift = 3 - e;
    const int d_in = DMODEL >> shift;
    const int d_hid = d_in * 4;
    const int n0 = nt * 128;
    const int cnt = counts[e];
    const int m0 = blockIdx.x * 128;
    if (m0 >= cnt) return;
    const int* lst = list + e * T_TOK;
    const unsigned long long hb = hbase[e];

    __shared__ short Abuf[128 * 64];
    __shared__ short Bbuf[128 * 64];

    const int tid = threadIdx.x;
    const int lane = tid & 63;
    const int w = tid >> 6;
    const int wm = (w >> 1) * 64;
    const int wn = (w & 1) * 64;
    const int lrow = lane >> 3;           // 0..7 (row within 8-row group)
    const int lch = lane & 7;             // lds slot
    const int gch = lch ^ lrow;           // swizzled global chunk

    // gather token ids once (4 per wave: rows w*32 + j*8 + lrow)
    int tokA[4];
#pragma unroll
    for (int j = 0; j < 4; ++j) {
        int rr = m0 + w * 32 + j * 8 + lrow;
        if (rr >= cnt) rr = cnt - 1;
        tokA[j] = lst[rr];
    }

    f32x4 acc[4][4];
#pragma unroll
    for (int i = 0; i < 4; ++i)
#pragma unroll
        for (int j = 0; j < 4; ++j)
            acc[i][j] = (f32x4){0.f, 0.f, 0.f, 0.f};

    for (int k0 = 0; k0 < d_in; k0 += 64) {
#pragma unroll
        for (int j = 0; j < 4; ++j) {
            const short* ga = xbf + (size_t)tokA[j] * DMODEL + k0 + gch * 8;
            gl_lds16(ga, &Abuf[(w * 32 + j * 8) * 64]);
            const short* gb = w1bf + (size_t)(n0 + w * 32 + j * 8 + lrow) * DMODEL + k0 + gch * 8;
            gl_lds16(gb, &Bbuf[(w * 32 + j * 8) * 64]);
        }
        __syncthreads();
#pragma unroll
        for (int kk = 0; kk < 2; ++kk) {
            short8_t af[4], bfr[4];
            const int q = (lane >> 4) + kk * 4;
#pragma unroll
            for (int mt = 0; mt < 4; ++mt) {
                int row = wm + mt * 16 + (lane & 15);
                af[mt] = *(const short8_t*)&Abuf[((row << 3) | (q ^ (row & 7))) << 3];
            }
#pragma unroll
            for (int ntn = 0; ntn < 4; ++ntn) {
                int row = wn + ntn * 16 + (lane & 15);
                bfr[ntn] = *(const short8_t*)&Bbuf[((row << 3) | (q ^ (row & 7))) << 3];
            }
#pragma unroll
            for (int mt = 0; mt < 4; ++mt)
#pragma unroll
                for (int ntn = 0; ntn < 4; ++ntn)
                    acc[mt][ntn] = __builtin_amdgcn_mfma_f32_16x16x32_bf16(
                        af[mt], bfr[ntn], acc[mt][ntn], 0, 0, 0);
        }
        __syncthreads();
    }

    const int col_l = lane & 15;
    const int qr = lane >> 4;
#pragma unroll
    for (int ntn = 0; ntn < 4; ++ntn) {
        int col = n0 + wn + ntn * 16 + col_l;
        float bias = b1[col];
#pragma unroll
        for (int mt = 0; mt < 4; ++mt) {
#pragma unroll
            for (int r = 0; r < 4; ++r) {
                int row = wm + mt * 16 + qr * 4 + r;
                if (m0 + row < cnt) {
                    float v = acc[mt][ntn][r] + bias;
                    hbuf[hb + (unsigned long long)(m0 + row) * d_hid + col] =
                        f2bf(gelu_exact(v));
                }
            }
        }
    }
}

// ---------------------------------------------------------------------------
// Pass 2: y[tok, :d_out] = h @ W2[:d_out, :d_hid]^T + b2  (DMA staged)
// blockIdx.y in [0,15): e0:1, e1:2, e2:4, e3:8 n-tiles.
// ---------------------------------------------------------------------------
__global__ __launch_bounds__(256) void k_pass2(
    const short* __restrict__ hbuf, const short* __restrict__ w2bf,
    const float* __restrict__ b2,
    const int* __restrict__ counts, const unsigned long long* __restrict__ hbase,
    const int* __restrict__ list, float* __restrict__ y)
{
    int by = blockIdx.y;
    int e, nt;
    if (by < 1)      { e = 0; nt = by; }
    else if (by < 3) { e = 1; nt = by - 1; }
    else if (by < 7) { e = 2; nt = by - 3; }
    else             { e = 3; nt = by - 7; }
    const int shift = 3 - e;
    const int d_in = DMODEL >> shift;
    const int d_hid = d_in * 4;
    const int n0 = nt * 128;
    const int cnt = counts[e];
    const int m0 = blockIdx.x * 128;
    if (m0 >= cnt) return;
    const int* lst = list + e * T_TOK;
    const unsigned long long hb = hbase[e];

    __shared__ short Abuf[128 * 64];
    __shared__ short Bbuf[128 * 64];

    const int tid = threadIdx.x;
    const int lane = tid & 63;
    const int w = tid >> 6;
    const int wm = (w >> 1) * 64;
    const int wn = (w & 1) * 64;
    const int lrow = lane >> 3;
    const int lch = lane & 7;
    const int gch = lch ^ lrow;

    // A rows are compact hbuf rows (no gather); clamp for partial tiles
    int rowA[4];
#pragma unroll
    for (int j = 0; j < 4; ++j) {
        int rr = m0 + w * 32 + j * 8 + lrow;
        if (rr >= cnt) rr = cnt - 1;
        rowA[j] = rr;
    }

    f32x4 acc[4][4];
#pragma unroll
    for (int i = 0; i < 4; ++i)
#pragma unroll
        for (int j = 0; j < 4; ++j)
            acc[i][j] = (f32x4){0.f, 0.f, 0.f, 0.f};

    for (int k0 = 0; k0 < d_hid; k0 += 64) {
#pragma unroll
        for (int j = 0; j < 4; ++j) {
            const short* ga = hbuf + hb + (size_t)rowA[j] * d_hid + k0 + gch * 8;
            gl_lds16(ga, &Abuf[(w * 32 + j * 8) * 64]);
            const short* gb = w2bf + (size_t)(n0 + w * 32 + j * 8 + lrow) * HDIM + k0 + gch * 8;
            gl_lds16(gb, &Bbuf[(w * 32 + j * 8) * 64]);
        }
        __syncthreads();
#pragma unroll
        for (int kk = 0; kk < 2; ++kk) {
            short8_t af[4], bfr[4];
            const int q = (lane >> 4) + kk * 4;
#pragma unroll
            for (int mt = 0; mt < 4; ++mt) {
                int row = wm + mt * 16 + (lane & 15);
                af[mt] = *(const short8_t*)&Abuf[((row << 3) | (q ^ (row & 7))) << 3];
            }
#pragma unroll
            for (int ntn = 0; ntn < 4; ++ntn) {
                int row = wn + ntn * 16 + (lane & 15);
                bfr[ntn] = *(const short8_t*)&Bbuf[((row << 3) | (q ^ (row & 7))) << 3];
            }
#pragma unroll
            for (int mt = 0; mt < 4; ++mt)
#pragma unroll
                for (int ntn = 0; ntn < 4; ++ntn)
                    acc[mt][ntn] = __builtin_amdgcn_mfma_f32_16x16x32_bf16(
                        af[mt], bfr[ntn], acc[mt][ntn], 0, 0, 0);
        }
        __syncthreads();
    }

    const int col_l = lane & 15;
    const int qr = lane >> 4;
#pragma unroll
    for (int ntn = 0; ntn < 4; ++ntn) {
        int col = n0 + wn + ntn * 16 + col_l;
        float bias = b2[col];
#pragma unroll
        for (int mt = 0; mt < 4; ++mt) {
#pragma unroll
            for (int r = 0; r < 4; ++r) {
                int row = wm + mt * 16 + qr * 4 + r;
                if (m0 + row < cnt) {
                    int tok = lst[m0 + row];
                    y[(size_t)tok * OUTD + col] = acc[mt][ntn][r] + bias;
                }
            }
        }
    }
}

extern "C" void kernel_launch(void* const* d_in, const int* in_sizes, int n_in,
                              void* d_out, int out_size, void* d_ws, size_t ws_size,
                              hipStream_t stream) {
    const float* x  = (const float*)d_in[0];
    const int* mask = (const int*)d_in[1];
    const float* w1 = (const float*)d_in[2];
    const float* b1 = (const float*)d_in[3];
    const float* w2 = (const float*)d_in[4];
    const float* b2 = (const float*)d_in[5];
    float* y = (float*)d_out;

    char* ws = (char*)d_ws;
    int* counts = (int*)(ws + WS_COUNTS_OFF);
    unsigned long long* hbase = (unsigned long long*)(ws + WS_HBASE_OFF);
    int* list = (int*)(ws + WS_LIST_OFF);
    short* xbf  = (short*)(ws + WS_XBF_OFF);
    short* w1bf = (short*)(ws + WS_W1BF_OFF);
    short* w2bf = (short*)(ws + WS_W2BF_OFF);
    short* hbuf = (short*)(ws + WS_HBUF_OFF);

    hipMemsetAsync(d_out, 0, (size_t)out_size * sizeof(float), stream);

    // convert x/w1/w2 -> bf16 (streaming, 8 elems/thread)
    const size_t tot8 = ((size_t)XN + W1N + W2N) / 8;   // 3,145,728
    k_convert<<<(unsigned)(tot8 / 256), 256, 0, stream>>>(x, w1, w2, xbf, w1bf, w2bf);

    k_init<<<1, 64, 0, stream>>>(counts);
    k_build<<<T_TOK / 256, 256, 0, stream>>>(mask, counts, list);
    k_bases<<<1, 1, 0, stream>>>(counts, hbase);

    k_pass1<<<dim3(128, 60), 256, 0, stream>>>(xbf, w1bf, b1, counts, hbase, list, hbuf);
    k_pass2<<<dim3(128, 15), 256, 0, stream>>>(hbuf, w2bf, b2, counts, hbase, list, y);
}

// Round 3
// 425.463 us; speedup vs baseline: 1.5371x; 1.2868x over previous
//
#include <hip/hip_runtime.h>
#include <hip/hip_bf16.h>

// B=4, N=4096 -> T=16384 tokens, D=1024, H=4096, OUT=1024, 4 nested experts.
#define T_TOK 16384
#define DMODEL 1024
#define HDIM 4096
#define OUTD 1024

typedef __attribute__((ext_vector_type(8))) short short8_t;  // 8 x bf16
typedef __attribute__((ext_vector_type(4))) float f32x4;     // MFMA acc

// ---- ws layout ----
#define WS_COUNTS_OFF 0
#define WS_HBASE_OFF 64
#define WS_LIST_OFF 128
#define WS_XBF_OFF  ((size_t)1 << 20)
#define WS_W1BF_OFF ((size_t)34 << 20)
#define WS_W2BF_OFF ((size_t)43 << 20)
#define WS_HBUF_OFF ((size_t)52 << 20)

#define XN (T_TOK * DMODEL)
#define W1N (HDIM * DMODEL)
#define W2N (OUTD * HDIM)

__device__ __forceinline__ short f2bf(float f) {
    union { float f; unsigned u; } x; x.f = f;
    unsigned r = x.u + 0x7FFFu + ((x.u >> 16) & 1u);  // RNE
    return (short)(r >> 16);
}

__device__ __forceinline__ float gelu_exact(float v) {
    return 0.5f * v * (1.0f + erff(v * 0.7071067811865476f));
}

__device__ __forceinline__ void conv8(const float* __restrict__ s, short* __restrict__ d) {
    const float4* s4 = (const float4*)s;
    float4 f0 = s4[0], f1 = s4[1];
    short8_t v;
    v[0] = f2bf(f0.x); v[1] = f2bf(f0.y); v[2] = f2bf(f0.z); v[3] = f2bf(f0.w);
    v[4] = f2bf(f1.x); v[5] = f2bf(f1.y); v[6] = f2bf(f1.z); v[7] = f2bf(f1.w);
    *(short8_t*)d = v;
}

__device__ __forceinline__ void gl_lds16(const short* g, short* lds) {
    __builtin_amdgcn_global_load_lds(
        (const __attribute__((address_space(1))) void*)g,
        (__attribute__((address_space(3))) void*)lds, 16, 0, 0);
}

__global__ void k_convert(const float* __restrict__ x, const float* __restrict__ w1,
                          const float* __restrict__ w2, short* __restrict__ xbf,
                          short* __restrict__ w1bf, short* __restrict__ w2bf) {
    size_t i8 = (size_t)blockIdx.x * blockDim.x + threadIdx.x;
    size_t elem = i8 * 8;
    if (elem < (size_t)XN) {
        conv8(x + elem, xbf + elem);
    } else if (elem < (size_t)XN + W1N) {
        size_t o = elem - XN; conv8(w1 + o, w1bf + o);
    } else {
        size_t o = elem - XN - W1N; conv8(w2 + o, w2bf + o);
    }
}

__global__ void k_init(int* counts) {
    if (threadIdx.x < 4) counts[threadIdx.x] = 0;
}

// LDS-histogram build: 256 global atomics total instead of 16384
__global__ void k_build(const int* __restrict__ mask, int* counts, int* list) {
    __shared__ int hcnt[4], hb[4], hpos[4];
    int tid = threadIdx.x;
    if (tid < 4) hcnt[tid] = 0;
    __syncthreads();
    int t = blockIdx.x * 256 + tid;
    int e = mask[t] & 3;
    atomicAdd(&hcnt[e], 1);
    __syncthreads();
    if (tid < 4) { hb[tid] = atomicAdd(&counts[tid], hcnt[tid]); hpos[tid] = 0; }
    __syncthreads();
    int p = atomicAdd(&hpos[e], 1);
    list[e * T_TOK + hb[e] + p] = t;
}

__global__ void k_bases(const int* counts, unsigned long long* hbase) {
    if (threadIdx.x == 0) {
        unsigned long long acc = 0;
        for (int e = 0; e < 4; ++e) {
            hbase[e] = acc;
            int d_hid = (DMODEL >> (3 - e)) * 4;
            acc += (unsigned long long)counts[e] * (unsigned long long)d_hid;
        }
    }
}

// ---------------------------------------------------------------------------
// Pass 1: h = gelu(x[:, :d_in] @ W1[:d_hid, :d_in]^T + b1)  (bf16 out)
// Double-buffered DMA pipeline: one barrier per k-step, DMA(k+1) overlaps
// compute(k). LDS 64KB -> 2 blocks/CU. m-stride over token tiles (grid bx=32).
// ---------------------------------------------------------------------------
__global__ __launch_bounds__(256) void k_pass1(
    const short* __restrict__ xbf, const short* __restrict__ w1bf,
    const float* __restrict__ b1,
    const int* __restrict__ counts, const unsigned long long* __restrict__ hbase,
    const int* __restrict__ list, short* __restrict__ hbuf)
{
    int by = blockIdx.y;
    int e, nt;
    if (by < 4)       { e = 0; nt = by; }
    else if (by < 12) { e = 1; nt = by - 4; }
    else if (by < 28) { e = 2; nt = by - 12; }
    else              { e = 3; nt = by - 28; }
    const int shift = 3 - e;
    const int d_in = DMODEL >> shift;
    const int d_hid = d_in * 4;
    const int n0 = nt * 128;
    const int cnt = counts[e];
    const int* lst = list + e * T_TOK;
    const unsigned long long hb = hbase[e];

    __shared__ short Abuf[2 * 128 * 64];   // 2 x 16KB
    __shared__ short Bbuf[2 * 128 * 64];

    const int tid = threadIdx.x;
    const int lane = tid & 63;
    const int w = tid >> 6;
    const int wm = (w >> 1) * 64;
    const int wn = (w & 1) * 64;
    const int lrow = lane >> 3;
    const int gch = (lane & 7) ^ lrow;     // swizzled global chunk

    for (int m0 = blockIdx.x * 128; m0 < cnt; m0 += 32 * 128) {
        int tokA[4];
#pragma unroll
        for (int j = 0; j < 4; ++j) {
            int rr = m0 + w * 32 + j * 8 + lrow;
            if (rr >= cnt) rr = cnt - 1;
            tokA[j] = lst[rr];
        }

        f32x4 acc[4][4];
#pragma unroll
        for (int i = 0; i < 4; ++i)
#pragma unroll
            for (int j = 0; j < 4; ++j)
                acc[i][j] = (f32x4){0.f, 0.f, 0.f, 0.f};

        const int ksteps = d_in >> 6;
        // prologue: stage k=0 into buffer 0
#pragma unroll
        for (int j = 0; j < 4; ++j) {
            gl_lds16(xbf + (size_t)tokA[j] * DMODEL + gch * 8,
                     &Abuf[(w * 32 + j * 8) * 64]);
            gl_lds16(w1bf + (size_t)(n0 + w * 32 + j * 8 + lrow) * DMODEL + gch * 8,
                     &Bbuf[(w * 32 + j * 8) * 64]);
        }
        for (int kt = 0; kt < ksteps; ++kt) {
            const int p = kt & 1;
            __syncthreads();   // drains buf[p] DMA; guards buf[1-p] reuse
            if (kt + 1 < ksteps) {
                const int knext = (kt + 1) << 6;
                const int q = 1 - p;
#pragma unroll
                for (int j = 0; j < 4; ++j) {
                    gl_lds16(xbf + (size_t)tokA[j] * DMODEL + knext + gch * 8,
                             &Abuf[(q * 128 + w * 32 + j * 8) * 64]);
                    gl_lds16(w1bf + (size_t)(n0 + w * 32 + j * 8 + lrow) * DMODEL + knext + gch * 8,
                             &Bbuf[(q * 128 + w * 32 + j * 8) * 64]);
                }
            }
            const short* Ab = &Abuf[p * 128 * 64];
            const short* Bb = &Bbuf[p * 128 * 64];
#pragma unroll
            for (int kk = 0; kk < 2; ++kk) {
                short8_t af[4], bfr[4];
                const int q = (lane >> 4) + kk * 4;
#pragma unroll
                for (int mt = 0; mt < 4; ++mt) {
                    int row = wm + mt * 16 + (lane & 15);
                    af[mt] = *(const short8_t*)&Ab[((row << 3) | (q ^ (row & 7))) << 3];
                }
#pragma unroll
                for (int ntn = 0; ntn < 4; ++ntn) {
                    int row = wn + ntn * 16 + (lane & 15);
                    bfr[ntn] = *(const short8_t*)&Bb[((row << 3) | (q ^ (row & 7))) << 3];
                }
#pragma unroll
                for (int mt = 0; mt < 4; ++mt)
#pragma unroll
                    for (int ntn = 0; ntn < 4; ++ntn)
                        acc[mt][ntn] = __builtin_amdgcn_mfma_f32_16x16x32_bf16(
                            af[mt], bfr[ntn], acc[mt][ntn], 0, 0, 0);
            }
        }
        __syncthreads();  // all reads of both buffers done before next m-iter stages

        const int col_l = lane & 15;
        const int qr = lane >> 4;
#pragma unroll
        for (int ntn = 0; ntn < 4; ++ntn) {
            int col = n0 + wn + ntn * 16 + col_l;
            float bias = b1[col];
#pragma unroll
            for (int mt = 0; mt < 4; ++mt) {
#pragma unroll
                for (int r = 0; r < 4; ++r) {
                    int row = wm + mt * 16 + qr * 4 + r;
                    if (m0 + row < cnt) {
                        float v = acc[mt][ntn][r] + bias;
                        hbuf[hb + (unsigned long long)(m0 + row) * d_hid + col] =
                            f2bf(gelu_exact(v));
                    }
                }
            }
        }
    }
}

// ---------------------------------------------------------------------------
// Pass 2: y[tok, :d_out] = h @ W2[:d_out, :d_hid]^T + b2; cols >= d_out
// zero-filled by the inactive n-tile blocks (replaces the 64MB memset).
// blockIdx.y in [0,32): e = by>>3, nt = by&7; active n-tiles = 8>>shift.
// ---------------------------------------------------------------------------
__global__ __launch_bounds__(256) void k_pass2(
    const short* __restrict__ hbuf, const short* __restrict__ w2bf,
    const float* __restrict__ b2,
    const int* __restrict__ counts, const unsigned long long* __restrict__ hbase,
    const int* __restrict__ list, float* __restrict__ y)
{
    const int by = blockIdx.y;
    const int e = by >> 3;
    const int nt = by & 7;
    const int shift = 3 - e;
    const int d_in = DMODEL >> shift;
    const int d_hid = d_in * 4;
    const int active = 8 >> shift;
    const int cnt = counts[e];
    const int* lst = list + e * T_TOK;
    const int n0 = nt * 128;
    const int tid = threadIdx.x;

    if (nt >= active) {
        // zero-fill y[tok, n0..n0+128) for this expert's tokens
        const float4 z = {0.f, 0.f, 0.f, 0.f};
        for (int m0 = blockIdx.x * 128; m0 < cnt; m0 += 32 * 128) {
            int row = m0 + (tid >> 1);
            if (row < cnt) {
                int tok = lst[row];
                float4* dst = (float4*)(y + (size_t)tok * OUTD + n0 + (tid & 1) * 64);
#pragma unroll
                for (int i = 0; i < 16; ++i) dst[i] = z;
            }
        }
        return;
    }

    const unsigned long long hb = hbase[e];

    __shared__ short Abuf[2 * 128 * 64];
    __shared__ short Bbuf[2 * 128 * 64];

    const int lane = tid & 63;
    const int w = tid >> 6;
    const int wm = (w >> 1) * 64;
    const int wn = (w & 1) * 64;
    const int lrow = lane >> 3;
    const int gch = (lane & 7) ^ lrow;

    for (int m0 = blockIdx.x * 128; m0 < cnt; m0 += 32 * 128) {
        int rowA[4];
#pragma unroll
        for (int j = 0; j < 4; ++j) {
            int rr = m0 + w * 32 + j * 8 + lrow;
            if (rr >= cnt) rr = cnt - 1;
            rowA[j] = rr;
        }

        f32x4 acc[4][4];
#pragma unroll
        for (int i = 0; i < 4; ++i)
#pragma unroll
            for (int j = 0; j < 4; ++j)
                acc[i][j] = (f32x4){0.f, 0.f, 0.f, 0.f};

        const int ksteps = d_hid >> 6;
#pragma unroll
        for (int j = 0; j < 4; ++j) {
            gl_lds16(hbuf + hb + (size_t)rowA[j] * d_hid + gch * 8,
                     &Abuf[(w * 32 + j * 8) * 64]);
            gl_lds16(w2bf + (size_t)(n0 + w * 32 + j * 8 + lrow) * HDIM + gch * 8,
                     &Bbuf[(w * 32 + j * 8) * 64]);
        }
        for (int kt = 0; kt < ksteps; ++kt) {
            const int p = kt & 1;
            __syncthreads();
            if (kt + 1 < ksteps) {
                const int knext = (kt + 1) << 6;
                const int q = 1 - p;
#pragma unroll
                for (int j = 0; j < 4; ++j) {
                    gl_lds16(hbuf + hb + (size_t)rowA[j] * d_hid + knext + gch * 8,
                             &Abuf[(q * 128 + w * 32 + j * 8) * 64]);
                    gl_lds16(w2bf + (size_t)(n0 + w * 32 + j * 8 + lrow) * HDIM + knext + gch * 8,
                             &Bbuf[(q * 128 + w * 32 + j * 8) * 64]);
                }
            }
            const short* Ab = &Abuf[p * 128 * 64];
            const short* Bb = &Bbuf[p * 128 * 64];
#pragma unroll
            for (int kk = 0; kk < 2; ++kk) {
                short8_t af[4], bfr[4];
                const int q = (lane >> 4) + kk * 4;
#pragma unroll
                for (int mt = 0; mt < 4; ++mt) {
                    int row = wm + mt * 16 + (lane & 15);
                    af[mt] = *(const short8_t*)&Ab[((row << 3) | (q ^ (row & 7))) << 3];
                }
#pragma unroll
                for (int ntn = 0; ntn < 4; ++ntn) {
                    int row = wn + ntn * 16 + (lane & 15);
                    bfr[ntn] = *(const short8_t*)&Bb[((row << 3) | (q ^ (row & 7))) << 3];
                }
#pragma unroll
                for (int mt = 0; mt < 4; ++mt)
#pragma unroll
                    for (int ntn = 0; ntn < 4; ++ntn)
                        acc[mt][ntn] = __builtin_amdgcn_mfma_f32_16x16x32_bf16(
                            af[mt], bfr[ntn], acc[mt][ntn], 0, 0, 0);
            }
        }
        __syncthreads();

        const int col_l = lane & 15;
        const int qr = lane >> 4;
#pragma unroll
        for (int ntn = 0; ntn < 4; ++ntn) {
            int col = n0 + wn + ntn * 16 + col_l;
            float bias = b2[col];
#pragma unroll
            for (int mt = 0; mt < 4; ++mt) {
#pragma unroll
                for (int r = 0; r < 4; ++r) {
                    int row = wm + mt * 16 + qr * 4 + r;
                    if (m0 + row < cnt) {
                        int tok = lst[m0 + row];
                        y[(size_t)tok * OUTD + col] = acc[mt][ntn][r] + bias;
                    }
                }
            }
        }
    }
}

extern "C" void kernel_launch(void* const* d_in, const int* in_sizes, int n_in,
                              void* d_out, int out_size, void* d_ws, size_t ws_size,
                              hipStream_t stream) {
    const float* x  = (const float*)d_in[0];
    const int* mask = (const int*)d_in[1];
    const float* w1 = (const float*)d_in[2];
    const float* b1 = (const float*)d_in[3];
    const float* w2 = (const float*)d_in[4];
    const float* b2 = (const float*)d_in[5];
    float* y = (float*)d_out;

    char* ws = (char*)d_ws;
    int* counts = (int*)(ws + WS_COUNTS_OFF);
    unsigned long long* hbase = (unsigned long long*)(ws + WS_HBASE_OFF);
    int* list = (int*)(ws + WS_LIST_OFF);
    short* xbf  = (short*)(ws + WS_XBF_OFF);
    short* w1bf = (short*)(ws + WS_W1BF_OFF);
    short* w2bf = (short*)(ws + WS_W2BF_OFF);
    short* hbuf = (short*)(ws + WS_HBUF_OFF);

    const size_t tot8 = ((size_t)XN + W1N + W2N) / 8;
    k_convert<<<(unsigned)(tot8 / 256), 256, 0, stream>>>(x, w1, w2, xbf, w1bf, w2bf);

    k_init<<<1, 64, 0, stream>>>(counts);
    k_build<<<T_TOK / 256, 256, 0, stream>>>(mask, counts, list);
    k_bases<<<1, 1, 0, stream>>>(counts, hbase);

    k_pass1<<<dim3(32, 60), 256, 0, stream>>>(xbf, w1bf, b1, counts, hbase, list, hbuf);
    k_pass2<<<dim3(32, 32), 256, 0, stream>>>(hbuf, w2bf, b2, counts, hbase, list, y);
}